// Round 1
// baseline (607.934 us; speedup 1.0000x reference)
//
#include <hip/hip_runtime.h>

#define D 128

// ---------------- CSR construction ----------------

__global__ __launch_bounds__(256) void k_hist(const int* __restrict__ dst, int* __restrict__ cnt, int E) {
    int i = blockIdx.x * 256 + threadIdx.x;
    if (i < E) atomicAdd(&cnt[dst[i]], 1);
}

__global__ __launch_bounds__(256) void k_scanA(const int* __restrict__ cnt, int* __restrict__ row_start,
                                               int* __restrict__ bsum, int N) {
    __shared__ int sd[256];
    int tid = threadIdx.x;
    int base = blockIdx.x * 1024 + tid * 4;
    int v0 = 0, v1 = 0, v2 = 0, v3 = 0;
    if (base + 0 < N) v0 = cnt[base + 0];
    if (base + 1 < N) v1 = cnt[base + 1];
    if (base + 2 < N) v2 = cnt[base + 2];
    if (base + 3 < N) v3 = cnt[base + 3];
    int s = v0 + v1 + v2 + v3;
    sd[tid] = s;
    __syncthreads();
    for (int off = 1; off < 256; off <<= 1) {
        int t = (tid >= off) ? sd[tid - off] : 0;
        __syncthreads();
        sd[tid] += t;
        __syncthreads();
    }
    if (tid == 255) bsum[blockIdx.x] = sd[255];
    int run = sd[tid] - s;  // exclusive within block
    if (base + 0 < N) row_start[base + 0] = run; run += v0;
    if (base + 1 < N) row_start[base + 1] = run; run += v1;
    if (base + 2 < N) row_start[base + 2] = run; run += v2;
    if (base + 3 < N) row_start[base + 3] = run;
}

__global__ void k_scanB(int* bsum, int nb) {
    if (threadIdx.x == 0 && blockIdx.x == 0) {
        int run = 0;
        for (int i = 0; i < nb; ++i) { int t = bsum[i]; bsum[i] = run; run += t; }
    }
}

__global__ __launch_bounds__(256) void k_scanC(int* __restrict__ row_start, int* __restrict__ cursor,
                                               const int* __restrict__ bsum, int N, int E) {
    int tid = threadIdx.x;
    int add = bsum[blockIdx.x];
    int base = blockIdx.x * 1024 + tid * 4;
    #pragma unroll
    for (int i = 0; i < 4; ++i) {
        int idx = base + i;
        if (idx < N) { int v = row_start[idx] + add; row_start[idx] = v; cursor[idx] = v; }
    }
    if (blockIdx.x == 0 && tid == 0) row_start[N] = E;
}

__global__ __launch_bounds__(256) void k_scatter(const int* __restrict__ src, const int* __restrict__ dst,
                                                 const float* __restrict__ dval, int* __restrict__ cursor,
                                                 int* __restrict__ csr_src, float* __restrict__ csr_d, int E) {
    int i = blockIdx.x * 256 + threadIdx.x;
    if (i < E) {
        int dd = dst[i];
        int pos = atomicAdd(&cursor[dd], 1);
        csr_src[pos] = src[i];
        csr_d[pos] = dval[i];
    }
}

// ---------------- fused dual GEMM: z = h@W1, zi = h@W2, a_src/a_dst dots ----------------
// Block: 256 threads, 64 rows. LDS: h tile transposed [k][r] (+1 pad), W chunk [32][128].
// Thread (tr=tid>>5, tc=tid&31) computes rows tr*8..tr*8+7 x cols tc*4..tc*4+3.

__global__ __launch_bounds__(256) void k_dual_gemm(
    const float* __restrict__ h, const float* __restrict__ W1, const float* __restrict__ W2,
    const float* __restrict__ Wa,
    float* __restrict__ z, float* __restrict__ zi,
    float* __restrict__ a_src, float* __restrict__ a_dst, int N)
{
    __shared__ float hT[128][65];   // [k][r]  33280 B
    __shared__ float wT[32][128];   // 16384 B
    int tid = threadIdx.x;
    int row0 = blockIdx.x * 64;

    for (int idx = tid; idx < 64 * 128; idx += 256) {
        int r = idx >> 7, k = idx & 127;
        float v = (row0 + r < N) ? h[(size_t)(row0 + r) * D + k] : 0.0f;
        hT[k][r] = v;
    }

    const int tr = tid >> 5;       // 0..7
    const int tc = tid & 31;       // 0..31
    const int rbase = tr * 8;
    const int cbase = tc * 4;

    for (int wsel = 0; wsel < 2; ++wsel) {
        const float* __restrict__ W = wsel ? W2 : W1;
        float acc[8][4];
        #pragma unroll
        for (int i = 0; i < 8; ++i)
            #pragma unroll
            for (int j = 0; j < 4; ++j) acc[i][j] = 0.0f;

        for (int k0 = 0; k0 < 128; k0 += 32) {
            __syncthreads();
            for (int idx = tid; idx < 32 * 128; idx += 256) {
                int kk = idx >> 7, c = idx & 127;
                wT[kk][c] = W[(size_t)(k0 + kk) * D + c];
            }
            __syncthreads();
            #pragma unroll
            for (int kk = 0; kk < 32; ++kk) {
                float hv[8], wv[4];
                #pragma unroll
                for (int i = 0; i < 8; ++i) hv[i] = hT[k0 + kk][rbase + i];
                #pragma unroll
                for (int j = 0; j < 4; ++j) wv[j] = wT[kk][cbase + j];
                #pragma unroll
                for (int i = 0; i < 8; ++i)
                    #pragma unroll
                    for (int j = 0; j < 4; ++j)
                        acc[i][j] = fmaf(hv[i], wv[j], acc[i][j]);
            }
        }

        float* __restrict__ out = wsel ? zi : z;
        #pragma unroll
        for (int i = 0; i < 8; ++i) {
            int r = row0 + rbase + i;
            if (r < N) {
                float4 v = make_float4(acc[i][0], acc[i][1], acc[i][2], acc[i][3]);
                *(float4*)&out[(size_t)r * D + cbase] = v;
            }
        }

        if (wsel == 0) {
            float wa_s[4], wa_d[4];
            #pragma unroll
            for (int j = 0; j < 4; ++j) { wa_s[j] = Wa[cbase + j]; wa_d[j] = Wa[128 + cbase + j]; }
            #pragma unroll
            for (int i = 0; i < 8; ++i) {
                float pa = 0.0f, pb = 0.0f;
                #pragma unroll
                for (int j = 0; j < 4; ++j) {
                    pa = fmaf(acc[i][j], wa_s[j], pa);
                    pb = fmaf(acc[i][j], wa_d[j], pb);
                }
                #pragma unroll
                for (int m = 1; m < 32; m <<= 1) { pa += __shfl_xor(pa, m); pb += __shfl_xor(pb, m); }
                if (tc == 0) {
                    int r = row0 + rbase + i;
                    if (r < N) { a_src[r] = pa; a_dst[r] = pb; }
                }
            }
        }
    }
}

// ---------------- per-node edge kernel: softmax over incoming edges + weighted aggregate ----------------
// One 64-lane wave per node. Lane owns 2 channels in pass C.

__global__ __launch_bounds__(256) void k_edge(
    const int* __restrict__ row_start, const int* __restrict__ csr_src, const float* __restrict__ csr_d,
    const float* __restrict__ z, const float* __restrict__ zi,
    const float* __restrict__ a_src, const float* __restrict__ a_dst,
    const float* __restrict__ W0l, const float* __restrict__ Wal,
    float* __restrict__ h_out, int N)
{
    int gt = blockIdx.x * 256 + threadIdx.x;
    int node = gt >> 6;
    int lane = threadIdx.x & 63;
    if (node >= N) return;

    float c0 = W0l[0] * Wal[2 * D];   // t * Wa[2D] coefficient on d[e]
    int rs = row_start[node];
    int re = row_start[node + 1];
    int deg = re - rs;
    float adst = a_dst[node];

    // pass A: max logit
    float mx = -INFINITY;
    for (int j = lane; j < deg; j += 64) {
        int s = csr_src[rs + j];
        float e = a_src[s] + adst + csr_d[rs + j] * c0;
        e = e > 0.0f ? e : 0.01f * e;
        mx = fmaxf(mx, e);
    }
    #pragma unroll
    for (int m = 1; m < 64; m <<= 1) mx = fmaxf(mx, __shfl_xor(mx, m));

    // pass B: sum of exp
    float sum = 0.0f;
    for (int j = lane; j < deg; j += 64) {
        int s = csr_src[rs + j];
        float e = a_src[s] + adst + csr_d[rs + j] * c0;
        e = e > 0.0f ? e : 0.01f * e;
        sum += __expf(e - mx);
    }
    #pragma unroll
    for (int m = 1; m < 64; m <<= 1) sum += __shfl_xor(sum, m);
    float inv = (deg > 0) ? 1.0f / sum : 0.0f;

    // pass C: weighted aggregate, lane owns channels {2*lane, 2*lane+1}
    int c = lane * 2;
    float acc0 = 0.0f, acc1 = 0.0f;
    for (int j = 0; j < deg; ++j) {
        int s = csr_src[rs + j];
        float e = a_src[s] + adst + csr_d[rs + j] * c0;
        e = e > 0.0f ? e : 0.01f * e;
        float alpha = __expf(e - mx) * inv;
        float2 zv = *(const float2*)&z[(size_t)s * D + c];
        acc0 = fmaf(alpha, zv.x, acc0);
        acc1 = fmaf(alpha, zv.y, acc1);
    }
    float2 ziv = *(const float2*)&zi[(size_t)node * D + c];
    float o0 = fmaxf(ziv.x + acc0, 0.0f);
    float o1 = fmaxf(ziv.y + acc1, 0.0f);
    *(float2*)&h_out[(size_t)node * D + c] = make_float2(o0, o1);
}

// ---------------- host launch ----------------

extern "C" void kernel_launch(void* const* d_in, const int* in_sizes, int n_in,
                              void* d_out, int out_size, void* d_ws, size_t ws_size,
                              hipStream_t stream) {
    const float* attr = (const float*)d_in[0];
    const float* dval = (const float*)d_in[1];
    const int*   src  = (const int*)d_in[2];
    const int*   dst  = (const int*)d_in[3];
    const float* W0   = (const float*)d_in[4];
    const float* W1   = (const float*)d_in[5];
    const float* W2   = (const float*)d_in[6];
    const float* Wa   = (const float*)d_in[7];

    int N = in_sizes[0] / D;
    int E = in_sizes[2];
    int L = in_sizes[4];

    char* ws = (char*)d_ws;
    size_t off = 0;
    auto alloc = [&](size_t bytes) -> void* {
        void* p = ws + off;
        off = (off + bytes + 255) & ~(size_t)255;
        return p;
    };
    int*   row_start = (int*)alloc((size_t)(N + 1) * 4);
    int*   cursor    = (int*)alloc((size_t)N * 4);
    int*   bsum      = (int*)alloc(4096);
    int*   csr_src   = (int*)alloc((size_t)E * 4);
    float* csr_d     = (float*)alloc((size_t)E * 4);
    float* zbuf      = (float*)alloc((size_t)N * D * 4);
    float* zibuf     = (float*)alloc((size_t)N * D * 4);
    float* a_src     = (float*)alloc((size_t)N * 4);
    float* a_dst     = (float*)alloc((size_t)N * 4);
    float* hA        = (float*)alloc((size_t)N * D * 4);
    float* hB        = (float*)alloc((size_t)N * D * 4);

    // CSR build (per launch; deterministic work)
    hipMemsetAsync(cursor, 0, (size_t)N * 4, stream);
    int ebl = (E + 255) / 256;
    k_hist<<<ebl, 256, 0, stream>>>(dst, cursor, E);
    int nb = (N + 1023) / 1024;
    k_scanA<<<nb, 256, 0, stream>>>(cursor, row_start, bsum, N);
    k_scanB<<<1, 1, 0, stream>>>(bsum, nb);
    k_scanC<<<nb, 256, 0, stream>>>(row_start, cursor, bsum, N, E);
    k_scatter<<<ebl, 256, 0, stream>>>(src, dst, dval, cursor, csr_src, csr_d, E);

    float* outp = (float*)d_out;
    const float* h_in = attr;
    for (int l = 0; l < L; ++l) {
        const float* W1l = W1 + (size_t)l * D * D;
        const float* W2l = W2 + (size_t)l * D * D;
        const float* Wal = Wa + (size_t)l * (2 * D + 1);
        const float* W0l = W0 + l;
        float* h_out;
        if (l == L - 1)      h_out = outp;
        else if ((l & 1) == 0) h_out = hA;
        else                 h_out = hB;

        k_dual_gemm<<<(N + 63) / 64, 256, 0, stream>>>(h_in, W1l, W2l, Wal, zbuf, zibuf, a_src, a_dst, N);
        int nblk = (N * 64 + 255) / 256;
        k_edge<<<nblk, 256, 0, stream>>>(row_start, csr_src, csr_d, zbuf, zibuf, a_src, a_dst, W0l, Wal, h_out, N);
        h_in = h_out;
    }
}

// Round 2
// 331.460 us; speedup vs baseline: 1.8341x; 1.8341x over previous
//
#include <hip/hip_runtime.h>

#define D 128

typedef __bf16 bf16x8 __attribute__((ext_vector_type(8)));
typedef float f32x4 __attribute__((ext_vector_type(4)));

__device__ __forceinline__ ushort f2bf(float f) {
    uint u = __float_as_uint(f);
    uint r = (u + 0x7FFFu + ((u >> 16) & 1u)) >> 16;
    return (ushort)r;
}
__device__ __forceinline__ float bf2f(ushort b) {
    return __uint_as_float(((uint)b) << 16);
}

// ---------------- CSR construction ----------------

__global__ __launch_bounds__(256) void k_hist(const int* __restrict__ dst, int* __restrict__ cnt, int E) {
    int i = blockIdx.x * 256 + threadIdx.x;
    if (i < E) atomicAdd(&cnt[dst[i]], 1);
}

__global__ __launch_bounds__(256) void k_scanA(const int* __restrict__ cnt, int* __restrict__ row_start,
                                               int* __restrict__ bsum, int N) {
    __shared__ int sd[256];
    int tid = threadIdx.x;
    int base = blockIdx.x * 1024 + tid * 4;
    int v0 = 0, v1 = 0, v2 = 0, v3 = 0;
    if (base + 0 < N) v0 = cnt[base + 0];
    if (base + 1 < N) v1 = cnt[base + 1];
    if (base + 2 < N) v2 = cnt[base + 2];
    if (base + 3 < N) v3 = cnt[base + 3];
    int s = v0 + v1 + v2 + v3;
    sd[tid] = s;
    __syncthreads();
    for (int off = 1; off < 256; off <<= 1) {
        int t = (tid >= off) ? sd[tid - off] : 0;
        __syncthreads();
        sd[tid] += t;
        __syncthreads();
    }
    if (tid == 255) bsum[blockIdx.x] = sd[255];
    int run = sd[tid] - s;  // exclusive within block
    if (base + 0 < N) row_start[base + 0] = run; run += v0;
    if (base + 1 < N) row_start[base + 1] = run; run += v1;
    if (base + 2 < N) row_start[base + 2] = run; run += v2;
    if (base + 3 < N) row_start[base + 3] = run;
}

__global__ void k_scanB(int* bsum, int nb) {
    if (threadIdx.x == 0 && blockIdx.x == 0) {
        int run = 0;
        for (int i = 0; i < nb; ++i) { int t = bsum[i]; bsum[i] = run; run += t; }
    }
}

__global__ __launch_bounds__(256) void k_scanC(int* __restrict__ row_start, int* __restrict__ cursor,
                                               const int* __restrict__ bsum, int N, int E) {
    int tid = threadIdx.x;
    int add = bsum[blockIdx.x];
    int base = blockIdx.x * 1024 + tid * 4;
    #pragma unroll
    for (int i = 0; i < 4; ++i) {
        int idx = base + i;
        if (idx < N) { int v = row_start[idx] + add; row_start[idx] = v; cursor[idx] = v; }
    }
    if (blockIdx.x == 0 && tid == 0) row_start[N] = E;
}

__global__ __launch_bounds__(256) void k_scatter(const int* __restrict__ src, const int* __restrict__ dst,
                                                 const float* __restrict__ dval, int* __restrict__ cursor,
                                                 int* __restrict__ csr_src, float* __restrict__ csr_d, int E) {
    int i = blockIdx.x * 256 + threadIdx.x;
    if (i < E) {
        int dd = dst[i];
        int pos = atomicAdd(&cursor[dd], 1);
        csr_src[pos] = src[i];
        csr_d[pos] = dval[i];
    }
}

// ---------------- prep: transpose+convert weights, convert attr ----------------

__global__ __launch_bounds__(256) void k_prep_w(const float* __restrict__ W1, const float* __restrict__ W2,
                                                ushort* __restrict__ wt, int L) {
    int l = blockIdx.x >> 1, m = blockIdx.x & 1;
    const float* W = (m ? W2 : W1) + (size_t)l * D * D;     // [k][n]
    ushort* o = wt + (size_t)(l * 2 + m) * D * D;            // [n][k]
    for (int idx = threadIdx.x; idx < D * D; idx += 256) {
        int k = idx >> 7, n = idx & 127;
        o[n * D + k] = f2bf(W[idx]);
    }
}

__global__ __launch_bounds__(256) void k_cvt(const float* __restrict__ in, ushort* __restrict__ out, int n4) {
    int i = blockIdx.x * 256 + threadIdx.x;
    if (i < n4) {
        float4 v = ((const float4*)in)[i];
        uint2 p;
        p.x = ((uint)f2bf(v.y) << 16) | (uint)f2bf(v.x);
        p.y = ((uint)f2bf(v.w) << 16) | (uint)f2bf(v.z);
        ((uint2*)out)[i] = p;
    }
}

// ---------------- fused dual GEMM via MFMA ----------------
// 1 wave per block-row-stripe of 16 rows. grid = N/16, block = 64.
// z = h@W1 (bf16 out), zi = h@W2 (fp32 out), a_src/a_dst epilogue dots.

__global__ __launch_bounds__(64) void k_dual_gemm_mfma(
    const ushort* __restrict__ hb, const ushort* __restrict__ Wt1, const ushort* __restrict__ Wt2,
    const float* __restrict__ Wa,
    ushort* __restrict__ z, float* __restrict__ zi,
    float* __restrict__ a_src, float* __restrict__ a_dst, int N)
{
    int lane = threadIdx.x;
    int rowbase = blockIdx.x * 16;
    int lm = lane & 15, kg = lane >> 4;
    int arow = rowbase + lm;

    bf16x8 af[4];
    #pragma unroll
    for (int k0 = 0; k0 < 4; ++k0)
        af[k0] = *(const bf16x8*)(hb + (size_t)arow * D + k0 * 32 + kg * 8);

    // ---- matrix 1: z = h @ W1 ----
    f32x4 acc[8];
    #pragma unroll
    for (int ct = 0; ct < 8; ++ct) acc[ct] = (f32x4){0.f, 0.f, 0.f, 0.f};
    #pragma unroll
    for (int ct = 0; ct < 8; ++ct) {
        const ushort* wb = Wt1 + (size_t)(ct * 16 + lm) * D + kg * 8;
        #pragma unroll
        for (int k0 = 0; k0 < 4; ++k0) {
            bf16x8 bfr = *(const bf16x8*)(wb + k0 * 32);
            acc[ct] = __builtin_amdgcn_mfma_f32_16x16x32_bf16(af[k0], bfr, acc[ct], 0, 0, 0);
        }
    }
    // write z (bf16) ; C layout: col=lane&15, row=kg*4+reg
    #pragma unroll
    for (int ct = 0; ct < 8; ++ct)
        #pragma unroll
        for (int r = 0; r < 4; ++r) {
            int row = rowbase + kg * 4 + r;
            z[(size_t)row * D + ct * 16 + lm] = f2bf(acc[ct][r]);
        }
    // a_src/a_dst dots from fp32 accumulators
    #pragma unroll
    for (int r = 0; r < 4; ++r) {
        float pa = 0.f, pb = 0.f;
        #pragma unroll
        for (int ct = 0; ct < 8; ++ct) {
            float v = acc[ct][r];
            pa = fmaf(v, Wa[ct * 16 + lm], pa);
            pb = fmaf(v, Wa[D + ct * 16 + lm], pb);
        }
        #pragma unroll
        for (int m = 1; m < 16; m <<= 1) { pa += __shfl_xor(pa, m); pb += __shfl_xor(pb, m); }
        if (lm == 0) {
            int row = rowbase + kg * 4 + r;
            a_src[row] = pa; a_dst[row] = pb;
        }
    }

    // ---- matrix 2: zi = h @ W2 (fp32 out) ----
    #pragma unroll
    for (int ct = 0; ct < 8; ++ct) acc[ct] = (f32x4){0.f, 0.f, 0.f, 0.f};
    #pragma unroll
    for (int ct = 0; ct < 8; ++ct) {
        const ushort* wb = Wt2 + (size_t)(ct * 16 + lm) * D + kg * 8;
        #pragma unroll
        for (int k0 = 0; k0 < 4; ++k0) {
            bf16x8 bfr = *(const bf16x8*)(wb + k0 * 32);
            acc[ct] = __builtin_amdgcn_mfma_f32_16x16x32_bf16(af[k0], bfr, acc[ct], 0, 0, 0);
        }
    }
    #pragma unroll
    for (int ct = 0; ct < 8; ++ct)
        #pragma unroll
        for (int r = 0; r < 4; ++r) {
            int row = rowbase + kg * 4 + r;
            zi[(size_t)row * D + ct * 16 + lm] = acc[ct][r];
        }
}

// ---------------- edge kernel: single-pass online softmax + aggregation ----------------
// One 64-lane wave per node; lane owns 2 channels (one packed bf16 pair of z).

__global__ __launch_bounds__(256) void k_edge(
    const int* __restrict__ row_start, const int* __restrict__ csr_src, const float* __restrict__ csr_d,
    const ushort* __restrict__ z, const float* __restrict__ zi,
    const float* __restrict__ a_src, const float* __restrict__ a_dst,
    const float* __restrict__ W0l, const float* __restrict__ Wal,
    ushort* __restrict__ out_bf, float* __restrict__ out_f32, int N)
{
    int node = (blockIdx.x * 256 + threadIdx.x) >> 6;
    int lane = threadIdx.x & 63;
    if (node >= N) return;

    float c0 = W0l[0] * Wal[2 * D];
    int rs = row_start[node];
    int deg = row_start[node + 1] - rs;
    float adst = a_dst[node];

    float denom = 0.f;
    float acc0 = 0.f, acc1 = 0.f;

    for (int base = 0; base < deg; base += 64) {
        int j = base + lane;
        bool valid = j < deg;
        int   s_l = valid ? csr_src[rs + j] : 0;
        float d_l = valid ? csr_d[rs + j] : 0.f;
        float e = a_src[s_l] + adst + d_l * c0;
        e = e > 0.f ? e : 0.01f * e;
        float ex = valid ? __expf(e) : 0.f;   // no max-shift: logits are O(few), exp is safe in fp32
        float t = ex;
        #pragma unroll
        for (int m = 1; m < 64; m <<= 1) t += __shfl_xor(t, m);
        denom += t;
        int cnt = deg - base; if (cnt > 64) cnt = 64;
        for (int jj = 0; jj < cnt; ++jj) {
            float w = __shfl(ex, jj);
            int   s = __shfl(s_l, jj);
            uint zv = ((const uint*)z)[(size_t)s * 64 + lane];
            acc0 = fmaf(w, __uint_as_float(zv << 16), acc0);
            acc1 = fmaf(w, __uint_as_float(zv & 0xFFFF0000u), acc1);
        }
    }
    float inv = (deg > 0) ? 1.0f / denom : 0.f;
    float2 zv = ((const float2*)zi)[(size_t)node * 64 + lane];
    float o0 = fmaxf(fmaf(acc0, inv, zv.x), 0.f);
    float o1 = fmaxf(fmaf(acc1, inv, zv.y), 0.f);
    if (out_f32) {
        ((float2*)out_f32)[(size_t)node * 64 + lane] = make_float2(o0, o1);
    } else {
        ((uint*)out_bf)[(size_t)node * 64 + lane] = ((uint)f2bf(o1) << 16) | (uint)f2bf(o0);
    }
}

// ---------------- host launch ----------------

extern "C" void kernel_launch(void* const* d_in, const int* in_sizes, int n_in,
                              void* d_out, int out_size, void* d_ws, size_t ws_size,
                              hipStream_t stream) {
    const float* attr = (const float*)d_in[0];
    const float* dval = (const float*)d_in[1];
    const int*   src  = (const int*)d_in[2];
    const int*   dst  = (const int*)d_in[3];
    const float* W0   = (const float*)d_in[4];
    const float* W1   = (const float*)d_in[5];
    const float* W2   = (const float*)d_in[6];
    const float* Wa   = (const float*)d_in[7];

    int N = in_sizes[0] / D;
    int E = in_sizes[2];
    int L = in_sizes[4];

    char* ws = (char*)d_ws;
    size_t off = 0;
    auto alloc = [&](size_t bytes) -> void* {
        void* p = ws + off;
        off = (off + bytes + 255) & ~(size_t)255;
        return p;
    };
    int*    row_start = (int*)alloc((size_t)(N + 1) * 4);
    int*    cursor    = (int*)alloc((size_t)N * 4);
    int*    bsum      = (int*)alloc(4096);
    int*    csr_src   = (int*)alloc((size_t)E * 4);
    float*  csr_d     = (float*)alloc((size_t)E * 4);
    ushort* zbuf      = (ushort*)alloc((size_t)N * D * 2);
    float*  zibuf     = (float*)alloc((size_t)N * D * 4);
    float*  a_src     = (float*)alloc((size_t)N * 4);
    float*  a_dst     = (float*)alloc((size_t)N * 4);
    ushort* hA        = (ushort*)alloc((size_t)N * D * 2);
    ushort* hB        = (ushort*)alloc((size_t)N * D * 2);
    ushort* attr_bf   = (ushort*)alloc((size_t)N * D * 2);
    ushort* wt        = (ushort*)alloc((size_t)L * 2 * D * D * 2);

    // CSR build
    hipMemsetAsync(cursor, 0, (size_t)N * 4, stream);
    int ebl = (E + 255) / 256;
    k_hist<<<ebl, 256, 0, stream>>>(dst, cursor, E);
    int nb = (N + 1023) / 1024;
    k_scanA<<<nb, 256, 0, stream>>>(cursor, row_start, bsum, N);
    k_scanB<<<1, 1, 0, stream>>>(bsum, nb);
    k_scanC<<<nb, 256, 0, stream>>>(row_start, cursor, bsum, N, E);
    k_scatter<<<ebl, 256, 0, stream>>>(src, dst, dval, cursor, csr_src, csr_d, E);

    // weight transpose + attr conversion
    k_prep_w<<<L * 2, 256, 0, stream>>>(W1, W2, wt, L);
    k_cvt<<<(N * D / 4 + 255) / 256, 256, 0, stream>>>(attr, attr_bf, N * D / 4);

    float* outp = (float*)d_out;
    const ushort* h_in = attr_bf;
    for (int l = 0; l < L; ++l) {
        const ushort* Wt1l = wt + (size_t)(l * 2 + 0) * D * D;
        const ushort* Wt2l = wt + (size_t)(l * 2 + 1) * D * D;
        const float*  Wal  = Wa + (size_t)l * (2 * D + 1);
        const float*  W0l  = W0 + l;

        k_dual_gemm_mfma<<<N / 16, 64, 0, stream>>>(h_in, Wt1l, Wt2l, Wal,
                                                    zbuf, zibuf, a_src, a_dst, N);

        ushort* hout_bf  = (l == L - 1) ? nullptr : ((l & 1) == 0 ? hA : hB);
        float*  hout_f32 = (l == L - 1) ? outp : nullptr;
        int nblk = (N * 64 + 255) / 256;
        k_edge<<<nblk, 256, 0, stream>>>(row_start, csr_src, csr_d, zbuf, zibuf,
                                         a_src, a_dst, W0l, Wal, hout_bf, hout_f32, N);
        h_in = (l & 1) == 0 ? hA : hB;
    }
}

// Round 3
// 271.482 us; speedup vs baseline: 2.2393x; 1.2209x over previous
//
#include <hip/hip_runtime.h>

#define D 128

typedef __bf16 bf16x8 __attribute__((ext_vector_type(8)));
typedef float f32x4 __attribute__((ext_vector_type(4)));

__device__ __forceinline__ ushort f2bf(float f) {
    uint u = __float_as_uint(f);
    uint r = (u + 0x7FFFu + ((u >> 16) & 1u)) >> 16;
    return (ushort)r;
}

// ---------------- CSR construction ----------------

__global__ __launch_bounds__(256) void k_hist(const int* __restrict__ dst, int* __restrict__ cnt, int E) {
    int i = blockIdx.x * 256 + threadIdx.x;
    if (i < E) atomicAdd(&cnt[dst[i]], 1);
}

__global__ __launch_bounds__(256) void k_scanA(const int* __restrict__ cnt, int* __restrict__ row_start,
                                               int* __restrict__ bsum, int N) {
    __shared__ int sd[256];
    int tid = threadIdx.x;
    int base = blockIdx.x * 1024 + tid * 4;
    int v0 = 0, v1 = 0, v2 = 0, v3 = 0;
    if (base + 0 < N) v0 = cnt[base + 0];
    if (base + 1 < N) v1 = cnt[base + 1];
    if (base + 2 < N) v2 = cnt[base + 2];
    if (base + 3 < N) v3 = cnt[base + 3];
    int s = v0 + v1 + v2 + v3;
    sd[tid] = s;
    __syncthreads();
    for (int off = 1; off < 256; off <<= 1) {
        int t = (tid >= off) ? sd[tid - off] : 0;
        __syncthreads();
        sd[tid] += t;
        __syncthreads();
    }
    if (tid == 255) bsum[blockIdx.x] = sd[255];
    int run = sd[tid] - s;  // exclusive within block
    if (base + 0 < N) row_start[base + 0] = run; run += v0;
    if (base + 1 < N) row_start[base + 1] = run; run += v1;
    if (base + 2 < N) row_start[base + 2] = run; run += v2;
    if (base + 3 < N) row_start[base + 3] = run;
}

__global__ void k_scanB(int* bsum, int nb) {
    int lane = threadIdx.x;  // 64 threads
    if (nb <= 64) {
        int v = (lane < nb) ? bsum[lane] : 0;
        int orig = v;
        #pragma unroll
        for (int off = 1; off < 64; off <<= 1) {
            int t = __shfl_up(v, off);
            if (lane >= off) v += t;
        }
        if (lane < nb) bsum[lane] = v - orig;
    } else if (lane == 0) {
        int run = 0;
        for (int i = 0; i < nb; ++i) { int t = bsum[i]; bsum[i] = run; run += t; }
    }
}

__global__ __launch_bounds__(256) void k_scanC(int* __restrict__ row_start, int* __restrict__ cursor,
                                               const int* __restrict__ bsum, int N, int E) {
    int tid = threadIdx.x;
    int add = bsum[blockIdx.x];
    int base = blockIdx.x * 1024 + tid * 4;
    #pragma unroll
    for (int i = 0; i < 4; ++i) {
        int idx = base + i;
        if (idx < N) { int v = row_start[idx] + add; row_start[idx] = v; cursor[idx] = v; }
    }
    if (blockIdx.x == 0 && tid == 0) row_start[N] = E;
}

__global__ __launch_bounds__(256) void k_scatter(const int* __restrict__ src, const int* __restrict__ dst,
                                                 const float* __restrict__ dval, int* __restrict__ cursor,
                                                 int* __restrict__ csr_src, float* __restrict__ csr_d, int E) {
    int i = blockIdx.x * 256 + threadIdx.x;
    if (i < E) {
        int dd = dst[i];
        int pos = atomicAdd(&cursor[dd], 1);
        csr_src[pos] = src[i];
        csr_d[pos] = dval[i];
    }
}

// ---------------- prep: transpose+convert weights, convert attr ----------------
// wt layout per layer: [2][128 n][128 k] bf16, row r = m*128+n holds W{m}^T row n.

__global__ __launch_bounds__(256) void k_prep_w(const float* __restrict__ W1, const float* __restrict__ W2,
                                                ushort* __restrict__ wt, int L) {
    int l = blockIdx.x >> 1, m = blockIdx.x & 1;
    const float* W = (m ? W2 : W1) + (size_t)l * D * D;     // [k][n]
    ushort* o = wt + (size_t)l * 2 * D * D + (size_t)m * D * D;  // [n][k]
    for (int idx = threadIdx.x; idx < D * D; idx += 256) {
        int k = idx >> 7, n = idx & 127;
        o[n * D + k] = f2bf(W[idx]);
    }
}

__global__ __launch_bounds__(256) void k_cvt(const float* __restrict__ in, ushort* __restrict__ out, int n4) {
    int i = blockIdx.x * 256 + threadIdx.x;
    if (i < n4) {
        float4 v = ((const float4*)in)[i];
        uint2 p;
        p.x = ((uint)f2bf(v.y) << 16) | (uint)f2bf(v.x);
        p.y = ((uint)f2bf(v.w) << 16) | (uint)f2bf(v.z);
        ((uint2*)out)[i] = p;
    }
}

// ---------------- fused dual GEMM via MFMA, weights in LDS (XOR-swizzled) ----------------
// 256 threads = 4 waves, 64 rows/block. LDS holds both 128x128 bf16 weight mats (64KB).

__global__ __launch_bounds__(256) void k_dual_gemm_mfma(
    const ushort* __restrict__ hb, const ushort* __restrict__ wt_layer,
    const float* __restrict__ Wa,
    ushort* __restrict__ z, float* __restrict__ zi,
    float* __restrict__ a_src, float* __restrict__ a_dst, int N)
{
    __shared__ ushort sw[2 * 128 * 128];   // 65536 B, rows r=0..255 of 256B, XOR-swizzled
    int tid = threadIdx.x;

    // stage 64KB: thread t copies 16 chunks of 16B; lds byte = r*256 + 16*(slot ^ (r&7))
    #pragma unroll 4
    for (int c = 0; c < 16; ++c) {
        int chunk = c * 256 + tid;          // 0..4095
        int r = chunk >> 4, slot = chunk & 15;
        uint4 v = *(const uint4*)(wt_layer + chunk * 8);
        *(uint4*)((char*)sw + r * 256 + ((slot ^ (r & 7)) << 4)) = v;
    }
    __syncthreads();

    int wv = tid >> 6, lane = tid & 63;
    int lm = lane & 15, kg = lane >> 4;
    int row0 = blockIdx.x * 64 + wv * 16;
    int arow = row0 + lm;
    if (arow >= N) arow = N - 1;

    bf16x8 af[4];
    #pragma unroll
    for (int k0 = 0; k0 < 4; ++k0)
        af[k0] = *(const bf16x8*)(hb + (size_t)arow * D + k0 * 32 + kg * 8);

    #pragma unroll
    for (int mat = 0; mat < 2; ++mat) {
        f32x4 acc[8];
        #pragma unroll
        for (int ct = 0; ct < 8; ++ct) acc[ct] = (f32x4){0.f, 0.f, 0.f, 0.f};

        #pragma unroll
        for (int ct = 0; ct < 8; ++ct) {
            int r = mat * 128 + ct * 16 + lm;
            const char* base = (const char*)sw + r * 256;
            int sx = (r & 7) << 4;
            #pragma unroll
            for (int k0 = 0; k0 < 4; ++k0) {
                bf16x8 bfr = *(const bf16x8*)(base + ((k0 * 64 + kg * 16) ^ sx));
                acc[ct] = __builtin_amdgcn_mfma_f32_16x16x32_bf16(af[k0], bfr, acc[ct], 0, 0, 0);
            }
        }

        if (mat == 0) {
            // z (bf16) ; C layout: col=lane&15, row=kg*4+reg
            #pragma unroll
            for (int ct = 0; ct < 8; ++ct)
                #pragma unroll
                for (int rr = 0; rr < 4; ++rr) {
                    int row = row0 + kg * 4 + rr;
                    if (row < N) z[(size_t)row * D + ct * 16 + lm] = f2bf(acc[ct][rr]);
                }
            // a_src/a_dst epilogue dots
            #pragma unroll
            for (int rr = 0; rr < 4; ++rr) {
                float pa = 0.f, pb = 0.f;
                #pragma unroll
                for (int ct = 0; ct < 8; ++ct) {
                    float v = acc[ct][rr];
                    pa = fmaf(v, Wa[ct * 16 + lm], pa);
                    pb = fmaf(v, Wa[D + ct * 16 + lm], pb);
                }
                #pragma unroll
                for (int m = 1; m < 16; m <<= 1) { pa += __shfl_xor(pa, m); pb += __shfl_xor(pb, m); }
                if (lm == 0) {
                    int row = row0 + kg * 4 + rr;
                    if (row < N) { a_src[row] = pa; a_dst[row] = pb; }
                }
            }
        } else {
            #pragma unroll
            for (int ct = 0; ct < 8; ++ct)
                #pragma unroll
                for (int rr = 0; rr < 4; ++rr) {
                    int row = row0 + kg * 4 + rr;
                    if (row < N) zi[(size_t)row * D + ct * 16 + lm] = acc[ct][rr];
                }
        }
    }
}

// ---------------- edge kernel: 4 edge slots x 16 channel lanes ----------------
// One wave per node. Lane (es=lane>>4, cl=lane&15): es = edge slot, cl = 8-channel group.

__global__ __launch_bounds__(256) void k_edge(
    const int* __restrict__ row_start, const int* __restrict__ csr_src, const float* __restrict__ csr_d,
    const ushort* __restrict__ z, const float* __restrict__ zi,
    const float* __restrict__ a_src, const float* __restrict__ a_dst,
    const float* __restrict__ W0l, const float* __restrict__ Wal,
    ushort* __restrict__ out_bf, float* __restrict__ out_f32, int N)
{
    int node = (blockIdx.x * 256 + threadIdx.x) >> 6;
    int lane = threadIdx.x & 63;
    if (node >= N) return;

    float c0 = W0l[0] * Wal[2 * D];
    int rs = row_start[node];
    int deg = row_start[node + 1] - rs;
    float adst = a_dst[node];
    int cl = lane & 15, es = lane >> 4;

    float acc[8] = {0.f, 0.f, 0.f, 0.f, 0.f, 0.f, 0.f, 0.f};
    float dsum = 0.f;

    #pragma unroll 4
    for (int base = 0; base < deg; base += 4) {
        int j = base + es;
        bool valid = j < deg;
        int   s_l = valid ? csr_src[rs + j] : 0;
        float d_l = valid ? csr_d[rs + j] : 0.f;
        float e = a_src[s_l] + adst + d_l * c0;
        e = e > 0.f ? e : 0.01f * e;
        float ex = valid ? __expf(e) : 0.f;   // no max-shift: softmax is shift-invariant, logits O(10)
        dsum += ex;                            // each edge counted by 16 lanes -> divide by 16 later
        uint4 zv = *(const uint4*)(z + (size_t)s_l * D + cl * 8);
        acc[0] = fmaf(ex, __uint_as_float(zv.x << 16), acc[0]);
        acc[1] = fmaf(ex, __uint_as_float(zv.x & 0xFFFF0000u), acc[1]);
        acc[2] = fmaf(ex, __uint_as_float(zv.y << 16), acc[2]);
        acc[3] = fmaf(ex, __uint_as_float(zv.y & 0xFFFF0000u), acc[3]);
        acc[4] = fmaf(ex, __uint_as_float(zv.z << 16), acc[4]);
        acc[5] = fmaf(ex, __uint_as_float(zv.z & 0xFFFF0000u), acc[5]);
        acc[6] = fmaf(ex, __uint_as_float(zv.w << 16), acc[6]);
        acc[7] = fmaf(ex, __uint_as_float(zv.w & 0xFFFF0000u), acc[7]);
    }

    // denominator: 64-lane reduce, each edge counted 16x
    #pragma unroll
    for (int m = 1; m < 64; m <<= 1) dsum += __shfl_xor(dsum, m);
    float inv = (deg > 0) ? 16.0f / dsum : 0.f;

    // sum acc over the 4 edge slots
    #pragma unroll
    for (int i = 0; i < 8; ++i) {
        acc[i] += __shfl_xor(acc[i], 16);
        acc[i] += __shfl_xor(acc[i], 32);
    }

    if (es == 0) {
        const float4* zp = (const float4*)(zi + (size_t)node * D + cl * 8);
        float4 z0 = zp[0], z1 = zp[1];
        float o0 = fmaxf(fmaf(acc[0], inv, z0.x), 0.f);
        float o1 = fmaxf(fmaf(acc[1], inv, z0.y), 0.f);
        float o2 = fmaxf(fmaf(acc[2], inv, z0.z), 0.f);
        float o3 = fmaxf(fmaf(acc[3], inv, z0.w), 0.f);
        float o4 = fmaxf(fmaf(acc[4], inv, z1.x), 0.f);
        float o5 = fmaxf(fmaf(acc[5], inv, z1.y), 0.f);
        float o6 = fmaxf(fmaf(acc[6], inv, z1.z), 0.f);
        float o7 = fmaxf(fmaf(acc[7], inv, z1.w), 0.f);
        if (out_f32) {
            float4* op = (float4*)(out_f32 + (size_t)node * D + cl * 8);
            op[0] = make_float4(o0, o1, o2, o3);
            op[1] = make_float4(o4, o5, o6, o7);
        } else {
            uint4 o;
            o.x = ((uint)f2bf(o1) << 16) | (uint)f2bf(o0);
            o.y = ((uint)f2bf(o3) << 16) | (uint)f2bf(o2);
            o.z = ((uint)f2bf(o5) << 16) | (uint)f2bf(o4);
            o.w = ((uint)f2bf(o7) << 16) | (uint)f2bf(o6);
            *(uint4*)(out_bf + (size_t)node * D + cl * 8) = o;
        }
    }
}

// ---------------- host launch ----------------

extern "C" void kernel_launch(void* const* d_in, const int* in_sizes, int n_in,
                              void* d_out, int out_size, void* d_ws, size_t ws_size,
                              hipStream_t stream) {
    const float* attr = (const float*)d_in[0];
    const float* dval = (const float*)d_in[1];
    const int*   src  = (const int*)d_in[2];
    const int*   dst  = (const int*)d_in[3];
    const float* W0   = (const float*)d_in[4];
    const float* W1   = (const float*)d_in[5];
    const float* W2   = (const float*)d_in[6];
    const float* Wa   = (const float*)d_in[7];

    int N = in_sizes[0] / D;
    int E = in_sizes[2];
    int L = in_sizes[4];

    char* ws = (char*)d_ws;
    size_t off = 0;
    auto alloc = [&](size_t bytes) -> void* {
        void* p = ws + off;
        off = (off + bytes + 255) & ~(size_t)255;
        return p;
    };
    int*    row_start = (int*)alloc((size_t)(N + 1) * 4);
    int*    cursor    = (int*)alloc((size_t)N * 4);
    int*    bsum      = (int*)alloc(4096);
    int*    csr_src   = (int*)alloc((size_t)E * 4);
    float*  csr_d     = (float*)alloc((size_t)E * 4);
    ushort* zbuf      = (ushort*)alloc((size_t)N * D * 2);
    float*  zibuf     = (float*)alloc((size_t)N * D * 4);
    float*  a_src     = (float*)alloc((size_t)N * 4);
    float*  a_dst     = (float*)alloc((size_t)N * 4);
    ushort* hA        = (ushort*)alloc((size_t)N * D * 2);
    ushort* hB        = (ushort*)alloc((size_t)N * D * 2);
    ushort* attr_bf   = (ushort*)alloc((size_t)N * D * 2);
    ushort* wt        = (ushort*)alloc((size_t)L * 2 * D * D * 2);

    // CSR build
    hipMemsetAsync(cursor, 0, (size_t)N * 4, stream);
    int ebl = (E + 255) / 256;
    k_hist<<<ebl, 256, 0, stream>>>(dst, cursor, E);
    int nb = (N + 1023) / 1024;
    k_scanA<<<nb, 256, 0, stream>>>(cursor, row_start, bsum, N);
    k_scanB<<<1, 64, 0, stream>>>(bsum, nb);
    k_scanC<<<nb, 256, 0, stream>>>(row_start, cursor, bsum, N, E);
    k_scatter<<<ebl, 256, 0, stream>>>(src, dst, dval, cursor, csr_src, csr_d, E);

    // weight transpose + attr conversion
    k_prep_w<<<L * 2, 256, 0, stream>>>(W1, W2, wt, L);
    k_cvt<<<(N * D / 4 + 255) / 256, 256, 0, stream>>>(attr, attr_bf, N * D / 4);

    float* outp = (float*)d_out;
    const ushort* h_in = attr_bf;
    for (int l = 0; l < L; ++l) {
        const ushort* wt_layer = wt + (size_t)l * 2 * D * D;
        const float*  Wal  = Wa + (size_t)l * (2 * D + 1);
        const float*  W0l  = W0 + l;

        k_dual_gemm_mfma<<<(N + 63) / 64, 256, 0, stream>>>(h_in, wt_layer, Wal,
                                                            zbuf, zibuf, a_src, a_dst, N);

        ushort* hout_bf  = (l == L - 1) ? nullptr : ((l & 1) == 0 ? hA : hB);
        float*  hout_f32 = (l == L - 1) ? outp : nullptr;
        int nblk = (N * 64 + 255) / 256;
        k_edge<<<nblk, 256, 0, stream>>>(row_start, csr_src, csr_d, zbuf, zibuf,
                                         a_src, a_dst, W0l, Wal, hout_bf, hout_f32, N);
        h_in = (l & 1) == 0 ? hA : hB;
    }
}

// Round 4
// 199.346 us; speedup vs baseline: 3.0496x; 1.3619x over previous
//
#include <hip/hip_runtime.h>

#define D 128

typedef __bf16 bf16x8 __attribute__((ext_vector_type(8)));
typedef float f32x4 __attribute__((ext_vector_type(4)));

__device__ __forceinline__ ushort f2bf(float f) {
    uint u = __float_as_uint(f);
    uint r = (u + 0x7FFFu + ((u >> 16) & 1u)) >> 16;
    return (ushort)r;
}

// ---------------- CSR construction ----------------

// one atomic pass: count AND record per-edge rank within its bucket
__global__ __launch_bounds__(256) void k_hist(const int* __restrict__ dst, int* __restrict__ cnt,
                                              int* __restrict__ rank, int E) {
    int i = blockIdx.x * 256 + threadIdx.x;
    if (i < E) rank[i] = atomicAdd(&cnt[dst[i]], 1);
}

__global__ __launch_bounds__(256) void k_scanA(const int* __restrict__ cnt, int* __restrict__ row_start,
                                               int* __restrict__ bsum, int N) {
    __shared__ int sd[256];
    int tid = threadIdx.x;
    int base = blockIdx.x * 1024 + tid * 4;
    int v0 = 0, v1 = 0, v2 = 0, v3 = 0;
    if (base + 0 < N) v0 = cnt[base + 0];
    if (base + 1 < N) v1 = cnt[base + 1];
    if (base + 2 < N) v2 = cnt[base + 2];
    if (base + 3 < N) v3 = cnt[base + 3];
    int s = v0 + v1 + v2 + v3;
    sd[tid] = s;
    __syncthreads();
    for (int off = 1; off < 256; off <<= 1) {
        int t = (tid >= off) ? sd[tid - off] : 0;
        __syncthreads();
        sd[tid] += t;
        __syncthreads();
    }
    if (tid == 255) bsum[blockIdx.x] = sd[255];
    int run = sd[tid] - s;  // exclusive within block
    if (base + 0 < N) row_start[base + 0] = run; run += v0;
    if (base + 1 < N) row_start[base + 1] = run; run += v1;
    if (base + 2 < N) row_start[base + 2] = run; run += v2;
    if (base + 3 < N) row_start[base + 3] = run;
}

__global__ void k_scanB(int* bsum, int nb) {
    int lane = threadIdx.x;  // 64 threads
    if (nb <= 64) {
        int v = (lane < nb) ? bsum[lane] : 0;
        int orig = v;
        #pragma unroll
        for (int off = 1; off < 64; off <<= 1) {
            int t = __shfl_up(v, off);
            if (lane >= off) v += t;
        }
        if (lane < nb) bsum[lane] = v - orig;
    } else if (lane == 0) {
        int run = 0;
        for (int i = 0; i < nb; ++i) { int t = bsum[i]; bsum[i] = run; run += t; }
    }
}

__global__ __launch_bounds__(256) void k_scanC(int* __restrict__ row_start,
                                               const int* __restrict__ bsum, int N, int E) {
    int tid = threadIdx.x;
    int add = bsum[blockIdx.x];
    int base = blockIdx.x * 1024 + tid * 4;
    #pragma unroll
    for (int i = 0; i < 4; ++i) {
        int idx = base + i;
        if (idx < N) row_start[idx] += add;
    }
    if (blockIdx.x == 0 && tid == 0) row_start[N] = E;
}

// no atomics: pos = row_start[dst] + rank; single packed 8B store
__global__ __launch_bounds__(256) void k_scatter(const int* __restrict__ src, const int* __restrict__ dst,
                                                 const float* __restrict__ dval,
                                                 const int* __restrict__ row_start, const int* __restrict__ rank,
                                                 int2* __restrict__ csr_sd, int E) {
    int i = blockIdx.x * 256 + threadIdx.x;
    if (i < E) {
        int d = dst[i];
        int pos = row_start[d] + rank[i];
        csr_sd[pos] = make_int2(src[i], __float_as_int(dval[i]));
    }
}

// ---------------- prep: transpose+convert weights, convert attr ----------------
// wt layout per layer: [2][128 n][128 k] bf16, row r = m*128+n holds W{m}^T row n.

__global__ __launch_bounds__(256) void k_prep_w(const float* __restrict__ W1, const float* __restrict__ W2,
                                                ushort* __restrict__ wt, int L) {
    int l = blockIdx.x >> 1, m = blockIdx.x & 1;
    const float* W = (m ? W2 : W1) + (size_t)l * D * D;     // [k][n]
    ushort* o = wt + (size_t)l * 2 * D * D + (size_t)m * D * D;  // [n][k]
    for (int idx = threadIdx.x; idx < D * D; idx += 256) {
        int k = idx >> 7, n = idx & 127;
        o[n * D + k] = f2bf(W[idx]);
    }
}

__global__ __launch_bounds__(256) void k_cvt(const float* __restrict__ in, ushort* __restrict__ out, int n4) {
    int i = blockIdx.x * 256 + threadIdx.x;
    if (i < n4) {
        float4 v = ((const float4*)in)[i];
        uint2 p;
        p.x = ((uint)f2bf(v.y) << 16) | (uint)f2bf(v.x);
        p.y = ((uint)f2bf(v.w) << 16) | (uint)f2bf(v.z);
        ((uint2*)out)[i] = p;
    }
}

// ---------------- fused dual GEMM via MFMA ----------------
// 512 threads = 8 waves, 128 rows/block. Both 128x128 bf16 weight mats staged to LDS
// (64KB) via global_load_lds with PRE-SWIZZLED global source (LDS dest linear).
// LDS semantic: lds[r][x] holds wt[r][x ^ (r&7)] (16B granules), so reads XOR with (r&7).

__global__ __launch_bounds__(512) void k_dual_gemm_mfma(
    const ushort* __restrict__ hb, const ushort* __restrict__ wt_layer,
    const float* __restrict__ Wa,
    ushort* __restrict__ z, ushort* __restrict__ zi,
    float* __restrict__ a_src, float* __restrict__ a_dst, int N)
{
    __shared__ ushort sw[2 * 128 * 128];   // 65536 B
    int tid = threadIdx.x;

    // stage 64KB direct-to-LDS: chunk = 16B granule index; dest linear, source swizzled
    #pragma unroll
    for (int it = 0; it < 8; ++it) {
        int chunk = it * 512 + tid;            // 0..4095
        int r = chunk >> 4, x = chunk & 15;
        const char* g = (const char*)wt_layer + (size_t)r * 256 + ((x ^ (r & 7)) << 4);
        __builtin_amdgcn_global_load_lds(
            (const __attribute__((address_space(1))) uint*)g,
            (__attribute__((address_space(3))) uint*)((char*)sw + (size_t)chunk * 16),
            16, 0, 0);
    }

    int wv = tid >> 6, lane = tid & 63;
    int lm = lane & 15, kg = lane >> 4;
    int row0 = blockIdx.x * 128 + wv * 16;
    int arow = row0 + lm;
    if (arow >= N) arow = N - 1;

    bf16x8 af[4];
    #pragma unroll
    for (int k0 = 0; k0 < 4; ++k0)
        af[k0] = *(const bf16x8*)(hb + (size_t)arow * D + k0 * 32 + kg * 8);

    asm volatile("s_waitcnt vmcnt(0)");
    __syncthreads();

    #pragma unroll
    for (int mat = 0; mat < 2; ++mat) {
        f32x4 acc[8];
        #pragma unroll
        for (int ct = 0; ct < 8; ++ct) acc[ct] = (f32x4){0.f, 0.f, 0.f, 0.f};

        #pragma unroll
        for (int ct = 0; ct < 8; ++ct) {
            int r = mat * 128 + ct * 16 + lm;
            const char* base = (const char*)sw + r * 256;
            int sx = (r & 7) << 4;
            #pragma unroll
            for (int k0 = 0; k0 < 4; ++k0) {
                bf16x8 bfr = *(const bf16x8*)(base + ((k0 * 64 + kg * 16) ^ sx));
                acc[ct] = __builtin_amdgcn_mfma_f32_16x16x32_bf16(af[k0], bfr, acc[ct], 0, 0, 0);
            }
        }

        ushort* __restrict__ outp = mat ? zi : z;
        // C layout: col=lane&15 (= lm), row=kg*4+reg
        #pragma unroll
        for (int ct = 0; ct < 8; ++ct)
            #pragma unroll
            for (int rr = 0; rr < 4; ++rr) {
                int row = row0 + kg * 4 + rr;
                if (row < N) outp[(size_t)row * D + ct * 16 + lm] = f2bf(acc[ct][rr]);
            }

        if (mat == 0) {
            // a_src/a_dst epilogue dots
            #pragma unroll
            for (int rr = 0; rr < 4; ++rr) {
                float pa = 0.f, pb = 0.f;
                #pragma unroll
                for (int ct = 0; ct < 8; ++ct) {
                    float v = acc[ct][rr];
                    pa = fmaf(v, Wa[ct * 16 + lm], pa);
                    pb = fmaf(v, Wa[D + ct * 16 + lm], pb);
                }
                #pragma unroll
                for (int m = 1; m < 16; m <<= 1) { pa += __shfl_xor(pa, m); pb += __shfl_xor(pb, m); }
                if (lm == 0) {
                    int row = row0 + kg * 4 + rr;
                    if (row < N) { a_src[row] = pa; a_dst[row] = pb; }
                }
            }
        }
    }
}

// ---------------- edge kernel: 4 edge slots x 16 channel lanes ----------------

__global__ __launch_bounds__(256) void k_edge(
    const int* __restrict__ row_start, const int2* __restrict__ csr_sd,
    const ushort* __restrict__ z, const ushort* __restrict__ zi,
    const float* __restrict__ a_src, const float* __restrict__ a_dst,
    const float* __restrict__ W0l, const float* __restrict__ Wal,
    ushort* __restrict__ out_bf, float* __restrict__ out_f32, int N)
{
    int node = (blockIdx.x * 256 + threadIdx.x) >> 6;
    int lane = threadIdx.x & 63;
    if (node >= N) return;

    float c0 = W0l[0] * Wal[2 * D];
    int rs = row_start[node];
    int deg = row_start[node + 1] - rs;
    float adst = a_dst[node];
    int cl = lane & 15, es = lane >> 4;

    float acc[8] = {0.f, 0.f, 0.f, 0.f, 0.f, 0.f, 0.f, 0.f};
    float dsum = 0.f;

    #pragma unroll 4
    for (int base = 0; base < deg; base += 4) {
        int j = base + es;
        bool valid = j < deg;
        int2 sd = csr_sd[rs + (valid ? j : 0)];
        float e = a_src[sd.x] + adst + __int_as_float(sd.y) * c0;
        e = e > 0.f ? e : 0.01f * e;
        float ex = valid ? __expf(e) : 0.f;   // no max-shift: softmax shift-invariant, logits O(10)
        dsum += ex;                            // each edge counted by 16 lanes -> scale by 16 later
        uint4 zv = *(const uint4*)(z + (size_t)sd.x * D + cl * 8);
        acc[0] = fmaf(ex, __uint_as_float(zv.x << 16), acc[0]);
        acc[1] = fmaf(ex, __uint_as_float(zv.x & 0xFFFF0000u), acc[1]);
        acc[2] = fmaf(ex, __uint_as_float(zv.y << 16), acc[2]);
        acc[3] = fmaf(ex, __uint_as_float(zv.y & 0xFFFF0000u), acc[3]);
        acc[4] = fmaf(ex, __uint_as_float(zv.z << 16), acc[4]);
        acc[5] = fmaf(ex, __uint_as_float(zv.z & 0xFFFF0000u), acc[5]);
        acc[6] = fmaf(ex, __uint_as_float(zv.w << 16), acc[6]);
        acc[7] = fmaf(ex, __uint_as_float(zv.w & 0xFFFF0000u), acc[7]);
    }

    #pragma unroll
    for (int m = 1; m < 64; m <<= 1) dsum += __shfl_xor(dsum, m);
    float inv = (deg > 0) ? 16.0f / dsum : 0.f;

    #pragma unroll
    for (int i = 0; i < 8; ++i) {
        acc[i] += __shfl_xor(acc[i], 16);
        acc[i] += __shfl_xor(acc[i], 32);
    }

    if (es == 0) {
        uint4 zr = *(const uint4*)(zi + (size_t)node * D + cl * 8);
        float zi0 = __uint_as_float(zr.x << 16),         zi1 = __uint_as_float(zr.x & 0xFFFF0000u);
        float zi2 = __uint_as_float(zr.y << 16),         zi3 = __uint_as_float(zr.y & 0xFFFF0000u);
        float zi4 = __uint_as_float(zr.z << 16),         zi5 = __uint_as_float(zr.z & 0xFFFF0000u);
        float zi6 = __uint_as_float(zr.w << 16),         zi7 = __uint_as_float(zr.w & 0xFFFF0000u);
        float o0 = fmaxf(fmaf(acc[0], inv, zi0), 0.f);
        float o1 = fmaxf(fmaf(acc[1], inv, zi1), 0.f);
        float o2 = fmaxf(fmaf(acc[2], inv, zi2), 0.f);
        float o3 = fmaxf(fmaf(acc[3], inv, zi3), 0.f);
        float o4 = fmaxf(fmaf(acc[4], inv, zi4), 0.f);
        float o5 = fmaxf(fmaf(acc[5], inv, zi5), 0.f);
        float o6 = fmaxf(fmaf(acc[6], inv, zi6), 0.f);
        float o7 = fmaxf(fmaf(acc[7], inv, zi7), 0.f);
        if (out_f32) {
            float4* op = (float4*)(out_f32 + (size_t)node * D + cl * 8);
            op[0] = make_float4(o0, o1, o2, o3);
            op[1] = make_float4(o4, o5, o6, o7);
        } else {
            uint4 o;
            o.x = ((uint)f2bf(o1) << 16) | (uint)f2bf(o0);
            o.y = ((uint)f2bf(o3) << 16) | (uint)f2bf(o2);
            o.z = ((uint)f2bf(o5) << 16) | (uint)f2bf(o4);
            o.w = ((uint)f2bf(o7) << 16) | (uint)f2bf(o6);
            *(uint4*)(out_bf + (size_t)node * D + cl * 8) = o;
        }
    }
}

// ---------------- host launch ----------------

extern "C" void kernel_launch(void* const* d_in, const int* in_sizes, int n_in,
                              void* d_out, int out_size, void* d_ws, size_t ws_size,
                              hipStream_t stream) {
    const float* attr = (const float*)d_in[0];
    const float* dval = (const float*)d_in[1];
    const int*   src  = (const int*)d_in[2];
    const int*   dst  = (const int*)d_in[3];
    const float* W0   = (const float*)d_in[4];
    const float* W1   = (const float*)d_in[5];
    const float* W2   = (const float*)d_in[6];
    const float* Wa   = (const float*)d_in[7];

    int N = in_sizes[0] / D;
    int E = in_sizes[2];
    int L = in_sizes[4];

    char* ws = (char*)d_ws;
    size_t off = 0;
    auto alloc = [&](size_t bytes) -> void* {
        void* p = ws + off;
        off = (off + bytes + 255) & ~(size_t)255;
        return p;
    };
    int*    row_start = (int*)alloc((size_t)(N + 1) * 4);
    int*    cnt       = (int*)alloc((size_t)N * 4);
    int*    bsum      = (int*)alloc(4096);
    int*    rank      = (int*)alloc((size_t)E * 4);
    int2*   csr_sd    = (int2*)alloc((size_t)E * 8);
    ushort* zbuf      = (ushort*)alloc((size_t)N * D * 2);
    ushort* zibuf     = (ushort*)alloc((size_t)N * D * 2);
    float*  a_src     = (float*)alloc((size_t)N * 4);
    float*  a_dst     = (float*)alloc((size_t)N * 4);
    ushort* hA        = (ushort*)alloc((size_t)N * D * 2);
    ushort* hB        = (ushort*)alloc((size_t)N * D * 2);
    ushort* attr_bf   = (ushort*)alloc((size_t)N * D * 2);
    ushort* wt        = (ushort*)alloc((size_t)L * 2 * D * D * 2);

    // CSR build (single atomic pass)
    hipMemsetAsync(cnt, 0, (size_t)N * 4, stream);
    int ebl = (E + 255) / 256;
    k_hist<<<ebl, 256, 0, stream>>>(dst, cnt, rank, E);
    int nb = (N + 1023) / 1024;
    k_scanA<<<nb, 256, 0, stream>>>(cnt, row_start, bsum, N);
    k_scanB<<<1, 64, 0, stream>>>(bsum, nb);
    k_scanC<<<nb, 256, 0, stream>>>(row_start, bsum, N, E);
    k_scatter<<<ebl, 256, 0, stream>>>(src, dst, dval, row_start, rank, csr_sd, E);

    // weight transpose + attr conversion
    k_prep_w<<<L * 2, 256, 0, stream>>>(W1, W2, wt, L);
    k_cvt<<<(N * D / 4 + 255) / 256, 256, 0, stream>>>(attr, attr_bf, N * D / 4);

    float* outp = (float*)d_out;
    const ushort* h_in = attr_bf;
    for (int l = 0; l < L; ++l) {
        const ushort* wt_layer = wt + (size_t)l * 2 * D * D;
        const float*  Wal  = Wa + (size_t)l * (2 * D + 1);
        const float*  W0l  = W0 + l;

        k_dual_gemm_mfma<<<(N + 127) / 128, 512, 0, stream>>>(h_in, wt_layer, Wal,
                                                              zbuf, zibuf, a_src, a_dst, N);

        ushort* hout_bf  = (l == L - 1) ? nullptr : ((l & 1) == 0 ? hA : hB);
        float*  hout_f32 = (l == L - 1) ? outp : nullptr;
        int nblk = (N * 64 + 255) / 256;
        k_edge<<<nblk, 256, 0, stream>>>(row_start, csr_sd, zbuf, zibuf,
                                         a_src, a_dst, W0l, Wal, hout_bf, hout_f32, N);
        h_in = (l & 1) == 0 ? hA : hB;
    }
}